// Round 11
// baseline (8132.592 us; speedup 1.0000x reference)
//
#include <hip/hip_runtime.h>
#include <hip/hip_bf16.h>
#include <stdint.h>

// Decoder: 2-layer LSTM, B=2048, T=96, H=1024, teacher forcing=1.0.
// Round 11: m201-style 8-phase 256x256 GEMM. 8 waves (4 gate-quarters x 2
// batch-halves), BK=64/K-tile, 2 K-tiles/iter, 128KB LDS. Per phase:
// {ds_read subtile || stage 1 half-tile} -> bar -> lgkm0 -> 16 MFMA -> bar.
// vmcnt(4) only at phases 4 and 8. Half-tile stagger: A(d1)@ph1-2,
// W(d0')@ph3-4, A(d0')@ph5-6, W(d1')@ph7-8. XOR swizzle slot^(row&7) both
// sides (R5-verified ~0 conflicts). L1 K padded to 1152 (zbuf).
// D_t = {L2(t) || L1(t+1)}, grid 256 = 1 block/CU.

#define BB   2048
#define TT   96
#define NG   4096
#define KL1P 1152     // [x 64 | h1 1024 | zeros 64]
#define KL2  2048     // [h1 | h2]

typedef __bf16 bf16;
typedef __bf16 bf16x8 __attribute__((ext_vector_type(8)));
typedef float  f32x4  __attribute__((ext_vector_type(4)));

__device__ __forceinline__ float sigm(float x) { return 1.0f / (1.0f + __expf(-x)); }
__device__ __forceinline__ float ftanh(float x) { return 2.0f / (1.0f + __expf(-2.0f * x)) - 1.0f; }

__device__ __forceinline__ void gload16(const bf16* g, bf16* l) {
  __builtin_amdgcn_global_load_lds((const __attribute__((address_space(1))) void*)g,
                                   (__attribute__((address_space(3))) void*)l, 16, 0, 0);
}

#define SB()  __builtin_amdgcn_sched_barrier(0)
#define BAR() __builtin_amdgcn_s_barrier()
#define PRIO1() __builtin_amdgcn_s_setprio(1)
#define PRIO0() __builtin_amdgcn_s_setprio(0)

// ---------------- prep kernels ----------------
// Weight rows permuted: out row n' = h*4 + gate  <-  in row gate*1024 + h.

__global__ __launch_bounds__(256) void build_w0(const float* __restrict__ Wih0,
                                                const float* __restrict__ Whh0,
                                                bf16* __restrict__ W0) {
  int idx = blockIdx.x * 256 + threadIdx.x;
  if (idx >= NG * KL1P) return;
  int np = idx / KL1P, k = idx % KL1P;
  int n = (np & 3) * 1024 + (np >> 2);
  float v;
  if (k < 60)        v = Wih0[n * 60 + k];
  else if (k < 64)   v = 0.0f;
  else if (k < 1088) v = Whh0[n * 1024 + (k - 64)];
  else               v = 0.0f;
  W0[idx] = (bf16)v;
}

__global__ __launch_bounds__(256) void build_w1(const float* __restrict__ Wih1,
                                                const float* __restrict__ Whh1,
                                                bf16* __restrict__ W1) {
  int idx = blockIdx.x * 256 + threadIdx.x;
  if (idx >= NG * KL2) return;
  int np = idx >> 11, k = idx & 2047;
  int n = (np & 3) * 1024 + (np >> 2);
  float v = (k < 1024) ? Wih1[n * 1024 + k] : Whh1[n * 1024 + (k - 1024)];
  W1[idx] = (bf16)v;
}

__global__ __launch_bounds__(256) void perm_bias(const float* __restrict__ b0,
                                                 const float* __restrict__ b1,
                                                 float* __restrict__ b0p,
                                                 float* __restrict__ b1p) {
  int idx = blockIdx.x * 256 + threadIdx.x;
  if (idx >= NG) return;
  int n = (idx & 3) * 1024 + (idx >> 2);
  b0p[idx] = b0[n];
  b1p[idx] = b1[n];
}

// X2 layout: [t][b][64]
__global__ __launch_bounds__(256) void build_x2(
    const float* __restrict__ dec, const float* __restrict__ ty, const float* __restrict__ lec,
    const int* __restrict__ gid, const int* __restrict__ cp, const int* __restrict__ cct,
    const int* __restrict__ cpt, const int* __restrict__ ccl,
    const float* __restrict__ gemb, const float* __restrict__ ep, const float* __restrict__ ect,
    const float* __restrict__ ept, const float* __restrict__ ecl,
    bf16* __restrict__ X2) {
  int idx = blockIdx.x * 256 + threadIdx.x;  // over T*B
  if (idx >= BB * TT) return;
  int t = idx >> 11, b = idx & 2047;
  bf16* x = X2 + (size_t)idx * 64;
  x[0] = (bf16)((t == 0) ? lec[b] : ty[b * TT + t - 1]);
  const float* d = dec + ((size_t)b * TT + t) * 32;
  #pragma unroll
  for (int k = 0; k < 32; ++k) x[1 + k] = (bf16)d[k];
  const float* e;
  e = ep  + cp[b]  * 4;  for (int j = 0; j < 4;  ++j) x[33 + j] = (bf16)e[j];
  e = ect + cct[b] * 2;  for (int j = 0; j < 2;  ++j) x[37 + j] = (bf16)e[j];
  e = ept + cpt[b] * 3;  for (int j = 0; j < 3;  ++j) x[39 + j] = (bf16)e[j];
  e = ecl + ccl[b] * 2;  for (int j = 0; j < 2;  ++j) x[42 + j] = (bf16)e[j];
  e = gemb + gid[b] * 16; for (int j = 0; j < 16; ++j) x[44 + j] = (bf16)e[j];
  for (int j = 60; j < 64; ++j) x[j] = (bf16)0.0f;
}

__global__ __launch_bounds__(256) void init_state(const float* __restrict__ enc_h,
                                                  const float* __restrict__ enc_c,
                                                  bf16* __restrict__ H1b,
                                                  bf16* __restrict__ H2b,
                                                  float* __restrict__ c1t,
                                                  float* __restrict__ c2t) {
  int idx = blockIdx.x * 256 + threadIdx.x;  // over B*H
  if (idx >= BB * 1024) return;
  int b = idx >> 10, h = idx & 1023;
  H1b[idx] = (bf16)enc_h[idx];
  H2b[idx] = (bf16)enc_h[(size_t)BB * 1024 + idx];
  c1t[(size_t)h * BB + b] = enc_c[idx];
  c2t[(size_t)h * BB + b] = enc_c[(size_t)BB * 1024 + idx];
}

// ---------------- 8-phase 256x256 GEMM + fused cell ----------------
// gates(b, n') = A(b,:) . W(n',:), n' = h*4 + gate. mfma(W_frag, A_frag):
// lane's f32x4 = {i,f,g,o} of one (b,h) cell.
// Wave w: wq = w&3 (64-gate quarter), wbh = w>>2 (128-batch half).
// acc[8 mf][4 gf]. LDS per operand: [2 dbuf][256 rows][64 k] bf16 = 64KB.
// Swizzle: stored 16B-slot s at row r holds source slot s ^ (r&7), both sides.

#define MMQ(MB, GB, A, W)                                                        \
  _Pragma("unroll") for (int m_ = 0; m_ < 4; ++m_)                               \
  _Pragma("unroll") for (int g_ = 0; g_ < 2; ++g_)                               \
  _Pragma("unroll") for (int k_ = 0; k_ < 2; ++k_)                               \
    acc[(MB) + m_][(GB) + g_] = __builtin_amdgcn_mfma_f32_16x16x32_bf16(         \
        W[g_ * 2 + k_], A[m_ * 2 + k_], acc[(MB) + m_][(GB) + g_], 0, 0, 0);

template <int MODE>  // 0: L1 (K=1152, A=[x|h1|0]) 1: L2 (K=2048, A=[h1|h2], +proj)
__device__ __forceinline__ void body(
    int tm, int tn, int t,
    const bf16* __restrict__ P0, const bf16* __restrict__ P1,
    const bf16* __restrict__ zbuf,
    const bf16* __restrict__ Wt, const float* __restrict__ bperm,
    float* __restrict__ ct, bf16* __restrict__ Hout,
    const float* __restrict__ wp, const float* __restrict__ bp,
    float* __restrict__ y, bf16* Al, bf16* Wl)
{
  constexpr int KT = MODE ? KL2 : KL1P;
  constexpr int NI = MODE ? 16 : 9;     // iters of 2 K-tiles (BK=64)

  const int tid = threadIdx.x;
  const int lane = tid & 63, w = tid >> 6;
  const int l15 = lane & 15, u = lane >> 4;
  const int wq = w & 3, wbh = w >> 2;

  f32x4 acc[8][4];
  #pragma unroll
  for (int i = 0; i < 8; ++i)
    #pragma unroll
    for (int j = 0; j < 4; ++j) acc[i][j] = (f32x4){0.f, 0.f, 0.f, 0.f};

  // staging: per call, wave covers LDS slots [w*128+q*64, +64) linearly.
  const int sx = (((lane & 7) ^ (lane >> 3)) << 3);   // swizzled source elems
  const int rsub = w * 16 + (lane >> 3);              // row within half (q*8 added)
  // read offsets: logical slot ks*4+u -> stored ^ (row&7) = ^(l15&7)
  const int jx0 = ((u) ^ (l15 & 7)) << 3;
  const int jx1 = ((4 + u) ^ (l15 & 7)) << 3;

  auto aRow = [&](int row, int kt) -> const bf16* {
    if constexpr (MODE == 1) {
      return (kt < 16) ? P0 + (size_t)(tm + row) * 1024 + kt * 64
                       : P1 + (size_t)(tm + row) * 1024 + (kt - 16) * 64;
    } else {
      if (kt == 0)  return P0 + (size_t)(tm + row) * 64;
      if (kt <= 16) return P1 + (size_t)(tm + row) * 1024 + (kt - 1) * 64;
      return zbuf;
    }
  };
  auto stageA = [&](int d, int half, int kt) {
    #pragma unroll
    for (int q = 0; q < 2; ++q) {
      int row = half * 128 + rsub + q * 8;
      gload16(aRow(row, kt) + sx, Al + d * 16384 + half * 8192 + (w * 128 + q * 64) * 8);
    }
  };
  auto stageW = [&](int d, int half, int kt) {
    #pragma unroll
    for (int q = 0; q < 2; ++q) {
      int row = half * 128 + rsub + q * 8;
      gload16(Wt + (size_t)(tn + row) * KT + kt * 64 + sx,
              Wl + d * 16384 + half * 8192 + (w * 128 + q * 64) * 8);
    }
  };
  auto LDA8 = [&](bf16x8* dst, int d, int mfb) {
    #pragma unroll
    for (int m = 0; m < 4; ++m) {
      const bf16* p = Al + d * 16384 + (wbh * 128 + (mfb + m) * 16 + l15) * 64;
      dst[m * 2 + 0] = *reinterpret_cast<const bf16x8*>(p + jx0);
      dst[m * 2 + 1] = *reinterpret_cast<const bf16x8*>(p + jx1);
    }
  };
  auto LDW4 = [&](bf16x8* dst, int d, int gfb) {
    #pragma unroll
    for (int g = 0; g < 2; ++g) {
      const bf16* p = Wl + d * 16384 + (wq * 64 + (gfb + g) * 16 + l15) * 64;
      dst[g * 2 + 0] = *reinterpret_cast<const bf16x8*>(p + jx0);
      dst[g * 2 + 1] = *reinterpret_cast<const bf16x8*>(p + jx1);
    }
  };

  // prologue: T0 full (d0) + T1 W halves (d1); vmcnt(4) => T0 landed.
  stageA(0, 0, 0); stageA(0, 1, 0); stageW(0, 0, 0); stageW(0, 1, 0);
  stageW(1, 0, 1); stageW(1, 1, 1);
  asm volatile("s_waitcnt vmcnt(4)" ::: "memory");
  SB(); BAR(); SB();

  bf16x8 a_[8], wlo[4], whi[4];

  for (int i = 0; i < NI; ++i) {
    const bool pre = (i + 1 < NI);
    const int tb = 2 * i + 1;

    // ph1: Q1(d0) = mf0-3 x gf0-1 ; stage A(d1,h0,tb)
    LDA8(a_, 0, 0); LDW4(wlo, 0, 0);
    stageA(1, 0, tb);
    asm volatile("s_waitcnt lgkmcnt(8)" ::: "memory");
    SB(); BAR();
    asm volatile("s_waitcnt lgkmcnt(0)" ::: "memory"); SB();
    PRIO1(); MMQ(0, 0, a_, wlo); PRIO0();
    SB(); BAR();

    // ph2: Q2(d0) = mf0-3 x gf2-3 ; stage A(d1,h1,tb)
    LDW4(whi, 0, 2);
    stageA(1, 1, tb);
    SB(); BAR();
    asm volatile("s_waitcnt lgkmcnt(0)" ::: "memory"); SB();
    PRIO1(); MMQ(0, 2, a_, whi); PRIO0();
    SB(); BAR();

    // ph3: Q3(d0) = mf4-7 x gf2-3 ; stage W(d0', h0)
    LDA8(a_, 0, 4);
    if (pre) stageW(0, 0, 2 * i + 2);
    SB(); BAR();
    asm volatile("s_waitcnt lgkmcnt(0)" ::: "memory"); SB();
    PRIO1(); MMQ(4, 2, a_, whi); PRIO0();
    SB(); BAR();

    // ph4: Q4(d0) = mf4-7 x gf0-1 ; stage W(d0', h1); vmcnt => d1 tile complete
    if (pre) stageW(0, 1, 2 * i + 2);
    SB(); BAR(); SB();
    PRIO1(); MMQ(4, 0, a_, wlo); PRIO0();
    if (pre) { asm volatile("s_waitcnt vmcnt(4)" ::: "memory"); }
    else     { asm volatile("s_waitcnt vmcnt(0)" ::: "memory"); }
    SB(); BAR();

    // ph5: Q1(d1) ; stage A(d0', h0)
    LDA8(a_, 1, 0); LDW4(wlo, 1, 0);
    if (pre) stageA(0, 0, 2 * i + 2);
    asm volatile("s_waitcnt lgkmcnt(8)" ::: "memory");
    SB(); BAR();
    asm volatile("s_waitcnt lgkmcnt(0)" ::: "memory"); SB();
    PRIO1(); MMQ(0, 0, a_, wlo); PRIO0();
    SB(); BAR();

    // ph6: Q2(d1) ; stage A(d0', h1)
    LDW4(whi, 1, 2);
    if (pre) stageA(0, 1, 2 * i + 2);
    SB(); BAR();
    asm volatile("s_waitcnt lgkmcnt(0)" ::: "memory"); SB();
    PRIO1(); MMQ(0, 2, a_, whi); PRIO0();
    SB(); BAR();

    // ph7: Q3(d1) ; stage W(d1', h0)
    LDA8(a_, 1, 4);
    if (pre) stageW(1, 0, 2 * i + 3);
    SB(); BAR();
    asm volatile("s_waitcnt lgkmcnt(0)" ::: "memory"); SB();
    PRIO1(); MMQ(4, 2, a_, whi); PRIO0();
    SB(); BAR();

    // ph8: Q4(d1) ; stage W(d1', h1); vmcnt => d0' tile complete
    if (pre) stageW(1, 1, 2 * i + 3);
    SB(); BAR(); SB();
    PRIO1(); MMQ(4, 0, a_, wlo); PRIO0();
    if (pre) { asm volatile("s_waitcnt vmcnt(4)" ::: "memory"); }
    else     { asm volatile("s_waitcnt vmcnt(0)" ::: "memory"); }
    SB(); BAR();
  }

  SB(); BAR(); SB();   // LDS free for epilogue reuse

  // ---- fused cell epilogue ----
  bf16* hst = Al + w * 2048;            // per-wave [128 b][16 h] bf16 = 4KB
  const int hq = (tn >> 2) + wq * 16;   // wave h base (16 h values)
  const int bgb = tm + wbh * 128;       // wave batch base (128 rows)
  float yp[8] = {0.f, 0.f, 0.f, 0.f, 0.f, 0.f, 0.f, 0.f};

  #pragma unroll
  for (int gf = 0; gf < 4; ++gf) {
    int hg = hq + gf * 4 + u;
    f32x4 bv = *reinterpret_cast<const f32x4*>(&bperm[hg * 4]);
    float wph = 0.f;
    if constexpr (MODE == 1) wph = wp[hg];
    #pragma unroll
    for (int mf = 0; mf < 8; ++mf) {
      int bg = bgb + mf * 16 + l15;
      float gi = acc[mf][gf][0] + bv[0];
      float gf_ = acc[mf][gf][1] + bv[1];
      float gg = acc[mf][gf][2] + bv[2];
      float go = acc[mf][gf][3] + bv[3];
      float* cp_ = ct + (size_t)hg * BB + bg;
      float c = *cp_;
      float cn = sigm(gf_) * c + sigm(gi) * ftanh(gg);
      float hn = sigm(go) * ftanh(cn);
      *cp_ = cn;
      hst[(mf * 16 + l15) * 16 + gf * 4 + u] = (bf16)hn;
      if constexpr (MODE == 1) yp[mf] += hn * wph;
    }
  }

  asm volatile("s_waitcnt lgkmcnt(0)" ::: "memory"); SB();

  // coalesced H write: wave patch = 128 batch x 16 h
  #pragma unroll
  for (int q = 0; q < 4; ++q) {
    int chunk = q * 64 + lane;          // 0..255
    int row = chunk >> 1, h8 = chunk & 1;
    bf16x8 v = *reinterpret_cast<const bf16x8*>(&hst[row * 16 + h8 * 8]);
    *reinterpret_cast<bf16x8*>(&Hout[(size_t)(bgb + row) * 1024 + hq + h8 * 8]) = v;
  }

  if constexpr (MODE == 1) {
    #pragma unroll
    for (int mf = 0; mf < 8; ++mf) {
      float s = yp[mf];
      s += __shfl_xor(s, 16);
      s += __shfl_xor(s, 32);
      if (lane < 16)
        atomicAdd(&y[(size_t)(bgb + mf * 16 + lane) * TT + t], s);
    }
  } else {
    // init y[:, t] = b_proj before dispatch t's L2 atomics (tn==0 blocks)
    if (tn == 0 && tid < 256) y[(size_t)(tm + tid) * TT + t] = bp[0];
  }
}

// Grid 256: x = bid&7 (XCD), idx = bid>>3 in [0,32): mode = idx&1,
// q = idx>>1: tn = (x*2 + (q&1))*256, tm = (q>>1)*256.
// all_l1 (prologue): grid 128, idx in [0,16), mode=0, q=idx.
__global__ __launch_bounds__(512, 2) void step_kernel(
    const bf16* __restrict__ H1in, const bf16* __restrict__ H2in,
    bf16* __restrict__ H1out, bf16* __restrict__ H2out,
    const bf16* __restrict__ X2, const bf16* __restrict__ zbuf,
    const bf16* __restrict__ W0, const bf16* __restrict__ W1,
    const float* __restrict__ b0p, const float* __restrict__ b1p,
    float* __restrict__ c1t, float* __restrict__ c2t,
    const float* __restrict__ wp, const float* __restrict__ bp,
    float* __restrict__ y, int t2, int all_l1) {
  __shared__ alignas(16) bf16 Al[32768];   // 64 KB
  __shared__ alignas(16) bf16 Wl[32768];   // 64 KB
  int bid = (int)blockIdx.x;
  int x = bid & 7, idx = bid >> 3;
  int mode = all_l1 ? 0 : (idx & 1);
  int q = all_l1 ? idx : (idx >> 1);
  int tn = (x * 2 + (q & 1)) * 256;
  int tm = (q >> 1) * 256;
  if (mode == 0) {
    int t1 = t2 + 1;
    if (t1 >= TT) return;
    body<0>(tm, tn, t1, X2 + (size_t)t1 * BB * 64, H1in, zbuf,
            W0, b0p, c1t, H1out, nullptr, bp, y, Al, Wl);
  } else {
    body<1>(tm, tn, t2, H1in, H2in, zbuf,
            W1, b1p, c2t, H2out, wp, nullptr, y, Al, Wl);
  }
}

// ---------------- launch ----------------

extern "C" void kernel_launch(void* const* d_in, const int* in_sizes, int n_in,
                              void* d_out, int out_size, void* d_ws, size_t ws_size,
                              hipStream_t stream) {
  const float* dec   = (const float*)d_in[0];
  const float* ty    = (const float*)d_in[1];
  const float* enc_h = (const float*)d_in[2];
  const float* enc_c = (const float*)d_in[3];
  const float* lec   = (const float*)d_in[4];
  const int*   gid   = (const int*)d_in[5];
  const int*   cp    = (const int*)d_in[6];
  const int*   cct   = (const int*)d_in[7];
  const int*   cpt   = (const int*)d_in[8];
  const int*   ccl   = (const int*)d_in[9];
  const float* gemb  = (const float*)d_in[10];
  const float* ep    = (const float*)d_in[11];
  const float* ect   = (const float*)d_in[12];
  const float* ept   = (const float*)d_in[13];
  const float* ecl   = (const float*)d_in[14];
  const float* Wih0  = (const float*)d_in[15];
  const float* Whh0  = (const float*)d_in[16];
  const float* b0    = (const float*)d_in[17];
  const float* Wih1  = (const float*)d_in[18];
  const float* Whh1  = (const float*)d_in[19];
  const float* b1    = (const float*)d_in[20];
  const float* wp    = (const float*)d_in[21];
  const float* bp    = (const float*)d_in[22];
  float* y = (float*)d_out;

  char* ws = (char*)d_ws;
  bf16* W0    = (bf16*)ws;  ws += (size_t)NG * KL1P * 2;     //  9.4 MB
  bf16* W1    = (bf16*)ws;  ws += (size_t)NG * KL2 * 2;      // 16.8 MB
  bf16* X2    = (bf16*)ws;  ws += (size_t)BB * TT * 64 * 2;  // 25.2 MB
  bf16* H1a   = (bf16*)ws;  ws += (size_t)BB * 1024 * 2;     //  4.2 MB each
  bf16* H1b   = (bf16*)ws;  ws += (size_t)BB * 1024 * 2;
  bf16* H2a   = (bf16*)ws;  ws += (size_t)BB * 1024 * 2;
  bf16* H2b   = (bf16*)ws;  ws += (size_t)BB * 1024 * 2;
  float* c1t  = (float*)ws; ws += (size_t)BB * 1024 * 4;     //  8.4 MB
  float* c2t  = (float*)ws; ws += (size_t)BB * 1024 * 4;     //  8.4 MB
  float* b0p  = (float*)ws; ws += (size_t)NG * 4;
  float* b1p  = (float*)ws; ws += (size_t)NG * 4;
  bf16* zbuf  = (bf16*)ws;  ws += 256;                       // 128B zeros

  build_w0<<<(NG * KL1P + 255) / 256, 256, 0, stream>>>(Wih0, Whh0, W0);
  build_w1<<<(NG * KL2 + 255) / 256, 256, 0, stream>>>(Wih1, Whh1, W1);
  perm_bias<<<NG / 256, 256, 0, stream>>>(b0, b1, b0p, b1p);
  build_x2<<<(BB * TT + 255) / 256, 256, 0, stream>>>(dec, ty, lec, gid, cp, cct, cpt, ccl,
                                                      gemb, ep, ect, ept, ecl, X2);
  init_state<<<(BB * 1024) / 256, 256, 0, stream>>>(enc_h, enc_c, H1b, H2b, c1t, c2t);
  hipMemsetAsync(zbuf, 0, 256, stream);

  // prologue: L1(0) alone (grid 128). h1(t) in H1[t&1]; h2(t) in H2[t&1].
  step_kernel<<<128, 512, 0, stream>>>(H1b, nullptr, H1a, nullptr, X2, zbuf, W0, W1,
                                       b0p, b1p, c1t, c2t, wp, bp, y, -1, 1);
  for (int t = 0; t < TT; ++t) {
    bf16* h1i = (t & 1) ? H1b : H1a;
    bf16* h1o = (t & 1) ? H1a : H1b;
    bf16* h2i = (t & 1) ? H2a : H2b;
    bf16* h2o = (t & 1) ? H2b : H2a;
    step_kernel<<<256, 512, 0, stream>>>(h1i, h2i, h1o, h2o, X2, zbuf, W0, W1,
                                         b0p, b1p, c1t, c2t, wp, bp, y, t, 0);
  }
}

// Round 12
// 6973.013 us; speedup vs baseline: 1.1663x; 1.1663x over previous
//
#include <hip/hip_runtime.h>
#include <hip/hip_bf16.h>
#include <stdint.h>

// Decoder: 2-layer LSTM, B=2048, T=96, H=1024, teacher forcing=1.0.
// Round 12: W removed from LDS. W pre-arranged in global as per-lane MFMA
// fragments (coalesced 16B/lane loads, XCD-L2-resident, compiler-pipelined
// plain loads). LDS carries only A (16KB/block). 128x128 tiles, 4 waves of
// 64x64, counted vmcnt(6/4) + 2 raw barriers per K-iter, manual wfA/wfB
// rotation. Grid 768 = 512 L2 + 256 L1(double-tile): 3 blocks/CU balanced.

#define BB  2048
#define TT  96
#define NG  4096
#define NT0 34        // L1 K-iters (K=1088 = 2x32 x-part + 32x32 h-part)
#define NT1 64        // L2 K-iters (K=2048)

typedef __bf16 bf16;
typedef __bf16 bf16x8 __attribute__((ext_vector_type(8)));
typedef float  f32x4  __attribute__((ext_vector_type(4)));

__device__ __forceinline__ float sigm(float x) { return 1.0f / (1.0f + __expf(-x)); }
__device__ __forceinline__ float ftanh(float x) { return 2.0f / (1.0f + __expf(-2.0f * x)) - 1.0f; }

__device__ __forceinline__ void gload16(const bf16* g, bf16* l) {
  __builtin_amdgcn_global_load_lds((const __attribute__((address_space(1))) void*)g,
                                   (__attribute__((address_space(3))) void*)l, 16, 0, 0);
}

#define SB()  __builtin_amdgcn_sched_barrier(0)
#define BAR() __builtin_amdgcn_s_barrier()

// ---------------- prep kernels ----------------
// Gate-interleaved n' = h*4 + gate (orig row n = (n'&3)*1024 + (n'>>2)).
// Wfrag layout: [panel(32)][kt][wg(2)][mw(4)][lane(64)][j(8)],
//   n' = panel*128 + wg*64 + mw*16 + (lane&15), k = kt*32 + (lane>>4)*8 + j.

__global__ __launch_bounds__(256) void build_wf1(const float* __restrict__ Wih1,
                                                 const float* __restrict__ Whh1,
                                                 bf16* __restrict__ Wf) {
  int idx = blockIdx.x * 256 + threadIdx.x;      // 32*64*4096 = 8388608
  if (idx >= 32 * NT1 * 4096) return;
  int j = idx & 7, lane = (idx >> 3) & 63, mw = (idx >> 9) & 3;
  int wg = (idx >> 11) & 1, kt = (idx >> 12) & 63, panel = idx >> 18;
  int np = panel * 128 + wg * 64 + mw * 16 + (lane & 15);
  int k  = kt * 32 + ((lane >> 4) << 3) + j;
  int n  = (np & 3) * 1024 + (np >> 2);
  float v = (k < 1024) ? Wih1[n * 1024 + k] : Whh1[n * 1024 + (k - 1024)];
  Wf[idx] = (bf16)v;
}

__global__ __launch_bounds__(256) void build_wf0(const float* __restrict__ Wih0,
                                                 const float* __restrict__ Whh0,
                                                 bf16* __restrict__ Wf) {
  int idx = blockIdx.x * 256 + threadIdx.x;      // 32*34*4096 = 4456448
  if (idx >= 32 * NT0 * 4096) return;
  int j = idx & 7, lane = (idx >> 3) & 63, mw = (idx >> 9) & 3;
  int wg = (idx >> 11) & 1;
  int rem = idx >> 12;
  int kt = rem % NT0, panel = rem / NT0;
  int np = panel * 128 + wg * 64 + mw * 16 + (lane & 15);
  int k  = kt * 32 + ((lane >> 4) << 3) + j;
  int n  = (np & 3) * 1024 + (np >> 2);
  float v;
  if (k < 60)      v = Wih0[n * 60 + k];
  else if (k < 64) v = 0.0f;
  else             v = Whh0[n * 1024 + (k - 64)];
  Wf[idx] = (bf16)v;
}

__global__ __launch_bounds__(256) void perm_bias(const float* __restrict__ b0,
                                                 const float* __restrict__ b1,
                                                 float* __restrict__ b0p,
                                                 float* __restrict__ b1p) {
  int idx = blockIdx.x * 256 + threadIdx.x;
  if (idx >= NG) return;
  int n = (idx & 3) * 1024 + (idx >> 2);
  b0p[idx] = b0[n];
  b1p[idx] = b1[n];
}

// X layout: [b][t][64]
__global__ __launch_bounds__(256) void build_x(
    const float* __restrict__ dec, const float* __restrict__ ty, const float* __restrict__ lec,
    const int* __restrict__ gid, const int* __restrict__ cp, const int* __restrict__ cct,
    const int* __restrict__ cpt, const int* __restrict__ ccl,
    const float* __restrict__ gemb, const float* __restrict__ ep, const float* __restrict__ ect,
    const float* __restrict__ ept, const float* __restrict__ ecl,
    bf16* __restrict__ X) {
  int idx = blockIdx.x * 256 + threadIdx.x;  // over B*T
  if (idx >= BB * TT) return;
  int b = idx / TT, t = idx % TT;
  bf16* x = X + (size_t)idx * 64;
  x[0] = (bf16)((t == 0) ? lec[b] : ty[b * TT + t - 1]);
  const float* d = dec + (size_t)idx * 32;
  #pragma unroll
  for (int k = 0; k < 32; ++k) x[1 + k] = (bf16)d[k];
  const float* e;
  e = ep  + cp[b]  * 4;  for (int j = 0; j < 4;  ++j) x[33 + j] = (bf16)e[j];
  e = ect + cct[b] * 2;  for (int j = 0; j < 2;  ++j) x[37 + j] = (bf16)e[j];
  e = ept + cpt[b] * 3;  for (int j = 0; j < 3;  ++j) x[39 + j] = (bf16)e[j];
  e = ecl + ccl[b] * 2;  for (int j = 0; j < 2;  ++j) x[42 + j] = (bf16)e[j];
  e = gemb + gid[b] * 16; for (int j = 0; j < 16; ++j) x[44 + j] = (bf16)e[j];
  for (int j = 60; j < 64; ++j) x[j] = (bf16)0.0f;
}

__global__ __launch_bounds__(256) void init_state(const float* __restrict__ enc_h,
                                                  const float* __restrict__ enc_c,
                                                  bf16* __restrict__ H1b,
                                                  bf16* __restrict__ H2b,
                                                  float* __restrict__ c1t,
                                                  float* __restrict__ c2t) {
  int idx = blockIdx.x * 256 + threadIdx.x;  // over B*H
  if (idx >= BB * 1024) return;
  int b = idx >> 10, h = idx & 1023;
  H1b[idx] = (bf16)enc_h[idx];
  H2b[idx] = (bf16)enc_h[(size_t)BB * 1024 + idx];
  c1t[(size_t)h * BB + b] = enc_c[idx];
  c2t[(size_t)h * BB + b] = enc_c[(size_t)BB * 1024 + idx];
}

// ---------------- GEMM + fused cell: 128x128 tile, 4 waves of 64x64 ----------
// gates(b,n') = A(b,:).W(n',:). mfma(wf, af): lane's f32x4 = {i,f,g,o} of one
// (b,h) cell. Wave w: wb=w&1 (64-batch half), wg=w>>1 (64-gate half).
// A through LDS (2-way swizzle both sides, 16KB dbuf); W direct global->reg
// from Wfrag (coalesced, compiler-pipelined). 2 raw barriers + counted vmcnt.

template <int MODE>
__device__ __forceinline__ void body(
    int tm, int tn, int t,
    const bf16* __restrict__ P0, const bf16* __restrict__ P1,
    const bf16* __restrict__ Wf, const float* __restrict__ bperm,
    float* __restrict__ ct, bf16* __restrict__ Hout,
    const float* __restrict__ wp, const float* __restrict__ bp,
    float* __restrict__ y, bf16* As)
{
  constexpr int NT = MODE ? NT1 : NT0;

  const int tid = threadIdx.x;
  const int lane = tid & 63, w = tid >> 6;
  const int lrow = lane & 15, u = lane >> 4;
  const int wb = w & 1, wg = w >> 1;

  f32x4 acc[4][4];
  #pragma unroll
  for (int mw = 0; mw < 4; ++mw)
    #pragma unroll
    for (int nb = 0; nb < 4; ++nb) acc[mw][nb] = (f32x4){0.f, 0.f, 0.f, 0.f};

  // A staging: slots s = tid, 256+tid -> row = s>>2 (0..127), stored kslot s&3.
  // source kslot = (s&3) ^ ((row>>1)&3); read klocal inverts it.
  const int r0 = tid >> 2, r1 = (256 + tid) >> 2;
  const int kc0 = (((tid & 3) ^ ((r0 >> 1) & 3)) << 3);
  const int kc1 = (((tid & 3) ^ ((r1 >> 1) & 3)) << 3);
  const int d0 = (tid & ~63) * 8;
  const int d1 = 2048 + d0;
  const int klocal = ((((lane >> 4) ^ (lrow >> 1)) & 3) << 3);

  auto aptr = [&](int row, int kt, int kc) -> const bf16* {
    if constexpr (MODE == 0) {
      return (kt < 2) ? (P0 + ((size_t)(tm + row) * TT + t) * 64 + kt * 32 + kc)
                      : (P1 + (size_t)(tm + row) * 1024 + (kt - 2) * 32 + kc);
    } else {
      return (kt < 32) ? (P0 + (size_t)(tm + row) * 1024 + kt * 32 + kc)
                       : (P1 + (size_t)(tm + row) * 1024 + (kt - 32) * 32 + kc);
    }
  };
  auto stageA = [&](int kt, bf16* buf) {
    gload16(aptr(r0, kt, kc0), buf + d0);
    gload16(aptr(r1, kt, kc1), buf + d1);
  };

  // W fragment source: [panel][kt][wg][mw][lane][8]
  const bf16* wfbase = Wf + ((size_t)(tn >> 7) * NT) * 4096 + wg * 2048 + lane * 8;
  auto loadW = [&](bf16x8 (&wf)[4], int kt) {
    const bf16* p = wfbase + (size_t)kt * 4096;
    #pragma unroll
    for (int mw = 0; mw < 4; ++mw)
      wf[mw] = *reinterpret_cast<const bf16x8*>(p + mw * 512);
  };

  bf16x8 wfA[4], wfB[4];

  // prologue: A(0), wf(0), A(1) -> wait A(0)+wf(0) (leave A(1)'s 2 in flight)
  stageA(0, As);
  loadW(wfA, 0);
  stageA(1, As + 4096);
  asm volatile("s_waitcnt vmcnt(2)" ::: "memory");
  SB(); BAR(); SB();

  auto iter = [&](int kt, bf16x8 (&cur)[4], bf16x8 (&nxt)[4]) {
    bf16* buf = As + ((kt & 1) ? 4096 : 0);
    bf16x8 af[4];
    #pragma unroll
    for (int nb = 0; nb < 4; ++nb)
      af[nb] = *reinterpret_cast<const bf16x8*>(&buf[(wb * 64 + nb * 16 + lrow) * 32 + klocal]);
    asm volatile("s_waitcnt lgkmcnt(0)" ::: "memory");
    SB(); BAR(); SB();                   // all waves done reading buf
    if (kt + 2 < NT) stageA(kt + 2, buf);  // overwrite just-read buffer
    if (kt + 1 < NT) loadW(nxt, kt + 1);   // plain global loads, 1 iter ahead
    SB();
    __builtin_amdgcn_s_setprio(1);
    #pragma unroll
    for (int mw = 0; mw < 4; ++mw)
      #pragma unroll
      for (int nb = 0; nb < 4; ++nb)
        acc[mw][nb] = __builtin_amdgcn_mfma_f32_16x16x32_bf16(cur[mw], af[nb], acc[mw][nb], 0, 0, 0);
    __builtin_amdgcn_s_setprio(0);
    // A(kt+1) landed when everything newer than it (this iter's issues) allowed:
    if (kt + 2 < NT)      { asm volatile("s_waitcnt vmcnt(6)" ::: "memory"); }
    else if (kt + 1 < NT) { asm volatile("s_waitcnt vmcnt(4)" ::: "memory"); }
    else                  { asm volatile("s_waitcnt vmcnt(0)" ::: "memory"); }
    SB(); BAR(); SB();                   // all waves' A(kt+1) landed
  };

  for (int kt = 0; kt < NT; kt += 2) {
    iter(kt,     wfA, wfB);
    iter(kt + 1, wfB, wfA);
  }

  // ---- fused cell epilogue (hst = per-wave private region of As) ----
  bf16* hst = As + w * 1024;            // [64 b][16 h] bf16 = 2KB per wave
  const int hq = (tn >> 2) + wg * 16;   // wave h base (16 h values)
  const int bgb = tm + wb * 64;         // wave batch base (64 rows)
  float yp[4] = {0.f, 0.f, 0.f, 0.f};

  #pragma unroll
  for (int mw = 0; mw < 4; ++mw) {
    int hg = hq + mw * 4 + u;
    f32x4 bv = *reinterpret_cast<const f32x4*>(&bperm[hg * 4]);
    float wph = 0.f;
    if constexpr (MODE == 1) wph = wp[hg];
    #pragma unroll
    for (int nb = 0; nb < 4; ++nb) {
      int bg = bgb + nb * 16 + lrow;
      float gi = acc[mw][nb][0] + bv[0];
      float gf = acc[mw][nb][1] + bv[1];
      float gg = acc[mw][nb][2] + bv[2];
      float go = acc[mw][nb][3] + bv[3];
      float* cp_ = ct + (size_t)hg * BB + bg;
      float c = *cp_;
      float cn = sigm(gf) * c + sigm(gi) * ftanh(gg);
      float hn = sigm(go) * ftanh(cn);
      *cp_ = cn;
      hst[(nb * 16 + lrow) * 16 + mw * 4 + u] = (bf16)hn;
      if constexpr (MODE == 1) yp[nb] += hn * wph;
    }
  }

  asm volatile("s_waitcnt lgkmcnt(0)" ::: "memory");
  SB();

  // coalesced Hout write-out: wave patch = 64 batch x 16 h
  #pragma unroll
  for (int q = 0; q < 2; ++q) {
    int chunk = q * 64 + lane;
    int row = chunk >> 1, half = chunk & 1;
    bf16x8 v = *reinterpret_cast<const bf16x8*>(&hst[row * 16 + half * 8]);
    *reinterpret_cast<bf16x8*>(&Hout[(size_t)(bgb + row) * 1024 + hq + half * 8]) = v;
  }

  if constexpr (MODE == 1) {
    #pragma unroll
    for (int nb = 0; nb < 4; ++nb) {
      float s = yp[nb];
      s += __shfl_xor(s, 16);
      s += __shfl_xor(s, 32);
      if (lane < 16)
        atomicAdd(&y[(size_t)(bgb + nb * 16 + lane) * TT + t], s);
    }
  } else {
    // init y[:, t] = b_proj before dispatch t's L2 atomics (tn==0 blocks)
    if (tn == 0 && tid < 128) y[(size_t)(tm + tid) * TT + t] = bp[0];
  }
}

// Grid 768: bids [0,512) = L2(t) 128x128; [512,768) = L1(t+1), each doing TWO
// 128-wide tn tiles. all_l1 (prologue): grid 256.
// L2 decode: x=v&7, j=v>>3: tm=(j&15)*128, tn=(x*4+(j>>4))*128.
// L1 decode: x=v&7, j=v>>3: tm=(j&15)*128, tn0=(x*2+(j>>4))*256.
__global__ __launch_bounds__(256, 3) void step_kernel(
    const bf16* __restrict__ H1in, const bf16* __restrict__ H2in,
    bf16* __restrict__ H1out, bf16* __restrict__ H2out,
    const bf16* __restrict__ X,
    const bf16* __restrict__ Wf0, const bf16* __restrict__ Wf1,
    const float* __restrict__ b0p, const float* __restrict__ b1p,
    float* __restrict__ c1t, float* __restrict__ c2t,
    const float* __restrict__ wp, const float* __restrict__ bp,
    float* __restrict__ y, int t2, int only_l1) {
  __shared__ alignas(16) bf16 As[2 * 4096];   // 16 KB
  int bid = (int)blockIdx.x;
  if (only_l1 || bid >= 512) {
    int v = only_l1 ? bid : bid - 512;        // [0,256)
    int t1 = t2 + 1;
    if (t1 >= TT) return;
    int x = v & 7, j = v >> 3;
    int tm  = (j & 15) << 7;
    int tn0 = ((x << 1) + (j >> 4)) << 8;
    body<0>(tm, tn0, t1, X, H1in, Wf0, b0p, c1t, H1out, nullptr, bp, y, As);
    __syncthreads();                          // hst region safe before restage
    body<0>(tm, tn0 + 128, t1, X, H1in, Wf0, b0p, c1t, H1out, nullptr, bp, y, As);
  } else {
    int x = bid & 7, j = bid >> 3;
    int tm = (j & 15) << 7;
    int tn = ((x << 2) + (j >> 4)) << 7;
    body<1>(tm, tn, t2, H1in, H2in, Wf1, b1p, c2t, H2out, wp, nullptr, y, As);
  }
}

// ---------------- launch ----------------

extern "C" void kernel_launch(void* const* d_in, const int* in_sizes, int n_in,
                              void* d_out, int out_size, void* d_ws, size_t ws_size,
                              hipStream_t stream) {
  const float* dec   = (const float*)d_in[0];
  const float* ty    = (const float*)d_in[1];
  const float* enc_h = (const float*)d_in[2];
  const float* enc_c = (const float*)d_in[3];
  const float* lec   = (const float*)d_in[4];
  const int*   gid   = (const int*)d_in[5];
  const int*   cp    = (const int*)d_in[6];
  const int*   cct   = (const int*)d_in[7];
  const int*   cpt   = (const int*)d_in[8];
  const int*   ccl   = (const int*)d_in[9];
  const float* gemb  = (const float*)d_in[10];
  const float* ep    = (const float*)d_in[11];
  const float* ect   = (const float*)d_in[12];
  const float* ept   = (const float*)d_in[13];
  const float* ecl   = (const float*)d_in[14];
  const float* Wih0  = (const float*)d_in[15];
  const float* Whh0  = (const float*)d_in[16];
  const float* b0    = (const float*)d_in[17];
  const float* Wih1  = (const float*)d_in[18];
  const float* Whh1  = (const float*)d_in[19];
  const float* b1    = (const float*)d_in[20];
  const float* wp    = (const float*)d_in[21];
  const float* bp    = (const float*)d_in[22];
  float* y = (float*)d_out;

  char* ws = (char*)d_ws;
  bf16* Wf1   = (bf16*)ws;  ws += (size_t)32 * NT1 * 4096 * 2;  // 16.8 MB
  bf16* Wf0   = (bf16*)ws;  ws += (size_t)32 * NT0 * 4096 * 2;  //  8.9 MB
  bf16* X     = (bf16*)ws;  ws += (size_t)BB * TT * 64 * 2;     // 25.2 MB
  bf16* H1a   = (bf16*)ws;  ws += (size_t)BB * 1024 * 2;        //  4.2 MB each
  bf16* H1b   = (bf16*)ws;  ws += (size_t)BB * 1024 * 2;
  bf16* H2a   = (bf16*)ws;  ws += (size_t)BB * 1024 * 2;
  bf16* H2b   = (bf16*)ws;  ws += (size_t)BB * 1024 * 2;
  float* c1t  = (float*)ws; ws += (size_t)BB * 1024 * 4;        //  8.4 MB
  float* c2t  = (float*)ws; ws += (size_t)BB * 1024 * 4;        //  8.4 MB
  float* b0p  = (float*)ws; ws += (size_t)NG * 4;
  float* b1p  = (float*)ws; ws += (size_t)NG * 4;

  build_wf1<<<(32 * NT1 * 4096) / 256, 256, 0, stream>>>(Wih1, Whh1, Wf1);
  build_wf0<<<(32 * NT0 * 4096 + 255) / 256, 256, 0, stream>>>(Wih0, Whh0, Wf0);
  perm_bias<<<NG / 256, 256, 0, stream>>>(b0, b1, b0p, b1p);
  build_x<<<(BB * TT + 255) / 256, 256, 0, stream>>>(dec, ty, lec, gid, cp, cct, cpt, ccl,
                                                     gemb, ep, ect, ept, ecl, X);
  init_state<<<(BB * 1024) / 256, 256, 0, stream>>>(enc_h, enc_c, H1b, H2b, c1t, c2t);

  // prologue: L1(0) alone (grid 256). h1(t) in H1[t&1]; h2(t) in H2[t&1].
  step_kernel<<<256, 256, 0, stream>>>(H1b, nullptr, H1a, nullptr, X, Wf0, Wf1,
                                       b0p, b1p, c1t, c2t, wp, bp, y, -1, 1);
  for (int t = 0; t < TT; ++t) {
    bf16* h1i = (t & 1) ? H1b : H1a;
    bf16* h1o = (t & 1) ? H1a : H1b;
    bf16* h2i = (t & 1) ? H2a : H2b;
    bf16* h2o = (t & 1) ? H2b : H2a;
    step_kernel<<<768, 256, 0, stream>>>(h1i, h2i, h1o, h2o, X, Wf0, Wf1,
                                         b0p, b1p, c1t, c2t, wp, bp, y, t, 0);
  }
}

// Round 13
// 6392.350 us; speedup vs baseline: 1.2722x; 1.0908x over previous
//
#include <hip/hip_runtime.h>
#include <hip/hip_bf16.h>
#include <stdint.h>

// Decoder: 2-layer LSTM, B=2048, T=96, H=1024, teacher forcing=1.0.
// Round 13: R12 (W-in-registers from fragment-layout global buffer) with the
// per-wave tile doubled to 64 batch x 128 gates (32 MFMA per 4 A-ds_reads:
// halves LDS-bytes/FLOP, the diagnosed binding resource). Block 256 thr =
// 4 waves (2 wb x 2 wg), tile 128b x 256g, 2 blocks/CU. Grid 512 = 256 L2 +
// 256 L1, one of each per CU (98 iters balanced). Counted vmcnt, 2 barriers.

#define BB  2048
#define TT  96
#define NG  4096
#define NT0 34        // L1 K-iters (K=1088 = 2x32 x-part + 32x32 h-part)
#define NT1 64        // L2 K-iters (K=2048)

typedef __bf16 bf16;
typedef __bf16 bf16x8 __attribute__((ext_vector_type(8)));
typedef float  f32x4  __attribute__((ext_vector_type(4)));

__device__ __forceinline__ float sigm(float x) { return 1.0f / (1.0f + __expf(-x)); }
__device__ __forceinline__ float ftanh(float x) { return 2.0f / (1.0f + __expf(-2.0f * x)) - 1.0f; }

__device__ __forceinline__ void gload16(const bf16* g, bf16* l) {
  __builtin_amdgcn_global_load_lds((const __attribute__((address_space(1))) void*)g,
                                   (__attribute__((address_space(3))) void*)l, 16, 0, 0);
}

#define SB()  __builtin_amdgcn_sched_barrier(0)
#define BAR() __builtin_amdgcn_s_barrier()

// ---------------- prep kernels ----------------
// Gate-interleaved n' = h*4 + gate (orig row n = (n'&3)*1024 + (n'>>2)).
// Wfrag layout: [panel(16x256g)][kt][wg(2)][gf(8)][lane(64)][j(8)]:
//   n' = panel*256 + wg*128 + gf*16 + (lane&15), k = kt*32 + (lane>>4)*8 + j.
// Strides (elems): j 1, lane 8, gf 512, wg 4096, kt 8192, panel 8192*NT.

__global__ __launch_bounds__(256) void build_wf1(const float* __restrict__ Wih1,
                                                 const float* __restrict__ Whh1,
                                                 bf16* __restrict__ Wf) {
  int idx = blockIdx.x * 256 + threadIdx.x;      // 16*64*8192 = 8388608
  if (idx >= 16 * NT1 * 8192) return;
  int j = idx & 7, lane = (idx >> 3) & 63, gf = (idx >> 9) & 7;
  int wg = (idx >> 12) & 1, kt = (idx >> 13) & 63, panel = idx >> 19;
  int np = panel * 256 + wg * 128 + gf * 16 + (lane & 15);
  int k  = kt * 32 + ((lane >> 4) << 3) + j;
  int n  = (np & 3) * 1024 + (np >> 2);
  float v = (k < 1024) ? Wih1[n * 1024 + k] : Whh1[n * 1024 + (k - 1024)];
  Wf[idx] = (bf16)v;
}

__global__ __launch_bounds__(256) void build_wf0(const float* __restrict__ Wih0,
                                                 const float* __restrict__ Whh0,
                                                 bf16* __restrict__ Wf) {
  int idx = blockIdx.x * 256 + threadIdx.x;      // 16*34*8192 = 4456448
  if (idx >= 16 * NT0 * 8192) return;
  int j = idx & 7, lane = (idx >> 3) & 63, gf = (idx >> 9) & 7;
  int wg = (idx >> 12) & 1;
  int rem = idx >> 13;
  int kt = rem % NT0, panel = rem / NT0;
  int np = panel * 256 + wg * 128 + gf * 16 + (lane & 15);
  int k  = kt * 32 + ((lane >> 4) << 3) + j;
  int n  = (np & 3) * 1024 + (np >> 2);
  float v;
  if (k < 60)      v = Wih0[n * 60 + k];
  else if (k < 64) v = 0.0f;
  else             v = Whh0[n * 1024 + (k - 64)];
  Wf[idx] = (bf16)v;
}

__global__ __launch_bounds__(256) void perm_bias(const float* __restrict__ b0,
                                                 const float* __restrict__ b1,
                                                 float* __restrict__ b0p,
                                                 float* __restrict__ b1p) {
  int idx = blockIdx.x * 256 + threadIdx.x;
  if (idx >= NG) return;
  int n = (idx & 3) * 1024 + (idx >> 2);
  b0p[idx] = b0[n];
  b1p[idx] = b1[n];
}

// X layout: [b][t][64]
__global__ __launch_bounds__(256) void build_x(
    const float* __restrict__ dec, const float* __restrict__ ty, const float* __restrict__ lec,
    const int* __restrict__ gid, const int* __restrict__ cp, const int* __restrict__ cct,
    const int* __restrict__ cpt, const int* __restrict__ ccl,
    const float* __restrict__ gemb, const float* __restrict__ ep, const float* __restrict__ ect,
    const float* __restrict__ ept, const float* __restrict__ ecl,
    bf16* __restrict__ X) {
  int idx = blockIdx.x * 256 + threadIdx.x;  // over B*T
  if (idx >= BB * TT) return;
  int b = idx / TT, t = idx % TT;
  bf16* x = X + (size_t)idx * 64;
  x[0] = (bf16)((t == 0) ? lec[b] : ty[b * TT + t - 1]);
  const float* d = dec + (size_t)idx * 32;
  #pragma unroll
  for (int k = 0; k < 32; ++k) x[1 + k] = (bf16)d[k];
  const float* e;
  e = ep  + cp[b]  * 4;  for (int j = 0; j < 4;  ++j) x[33 + j] = (bf16)e[j];
  e = ect + cct[b] * 2;  for (int j = 0; j < 2;  ++j) x[37 + j] = (bf16)e[j];
  e = ept + cpt[b] * 3;  for (int j = 0; j < 3;  ++j) x[39 + j] = (bf16)e[j];
  e = ecl + ccl[b] * 2;  for (int j = 0; j < 2;  ++j) x[42 + j] = (bf16)e[j];
  e = gemb + gid[b] * 16; for (int j = 0; j < 16; ++j) x[44 + j] = (bf16)e[j];
  for (int j = 60; j < 64; ++j) x[j] = (bf16)0.0f;
}

__global__ __launch_bounds__(256) void init_state(const float* __restrict__ enc_h,
                                                  const float* __restrict__ enc_c,
                                                  bf16* __restrict__ H1b,
                                                  bf16* __restrict__ H2b,
                                                  float* __restrict__ c1t,
                                                  float* __restrict__ c2t) {
  int idx = blockIdx.x * 256 + threadIdx.x;  // over B*H
  if (idx >= BB * 1024) return;
  int b = idx >> 10, h = idx & 1023;
  H1b[idx] = (bf16)enc_h[idx];
  H2b[idx] = (bf16)enc_h[(size_t)BB * 1024 + idx];
  c1t[(size_t)h * BB + b] = enc_c[idx];
  c2t[(size_t)h * BB + b] = enc_c[(size_t)BB * 1024 + idx];
}

// ---------------- GEMM + fused cell: 128b x 256g tile, 4 waves of 64x128 ----
// gates(b,n') = A(b,:).W(n',:). mfma(wf, af): lane's f32x4 = {i,f,g,o} of one
// (b,h) cell: h = (tn>>2) + wg*32 + gf*4 + u, b = tm + wb*64 + bf*16 + l15.
// A via LDS (16KB dbuf, 2-way swizzle both sides); W via register fragments
// from Wfrag (coalesced 16B/lane, L1-shared by the wb-pair, double-buffered).

template <int MODE>
__device__ __forceinline__ void body(
    int tm, int tn, int t,
    const bf16* __restrict__ P0, const bf16* __restrict__ P1,
    const bf16* __restrict__ Wf, const float* __restrict__ bperm,
    float* __restrict__ ct, bf16* __restrict__ Hout,
    const float* __restrict__ wp, const float* __restrict__ bp,
    float* __restrict__ y, bf16* As)
{
  constexpr int NT = MODE ? NT1 : NT0;

  const int tid = threadIdx.x;
  const int lane = tid & 63, w = tid >> 6;
  const int lrow = lane & 15, u = lane >> 4;
  const int wb = w & 1, wg = w >> 1;

  f32x4 acc[8][4];
  #pragma unroll
  for (int gf = 0; gf < 8; ++gf)
    #pragma unroll
    for (int bf = 0; bf < 4; ++bf) acc[gf][bf] = (f32x4){0.f, 0.f, 0.f, 0.f};

  // A staging: slots s = tid, 256+tid -> row = s>>2 (0..127), stored kslot s&3.
  // source kslot = (s&3) ^ ((row>>1)&3); read klocal inverts it.
  const int r0 = tid >> 2, r1 = (256 + tid) >> 2;
  const int kc0 = (((tid & 3) ^ ((r0 >> 1) & 3)) << 3);
  const int kc1 = (((tid & 3) ^ ((r1 >> 1) & 3)) << 3);
  const int d0 = (tid & ~63) * 8;
  const int d1 = 2048 + d0;
  const int klocal = ((((lane >> 4) ^ (lrow >> 1)) & 3) << 3);

  auto aptr = [&](int row, int kt, int kc) -> const bf16* {
    if constexpr (MODE == 0) {
      return (kt < 2) ? (P0 + ((size_t)(tm + row) * TT + t) * 64 + kt * 32 + kc)
                      : (P1 + (size_t)(tm + row) * 1024 + (kt - 2) * 32 + kc);
    } else {
      return (kt < 32) ? (P0 + (size_t)(tm + row) * 1024 + kt * 32 + kc)
                       : (P1 + (size_t)(tm + row) * 1024 + (kt - 32) * 32 + kc);
    }
  };
  auto stageA = [&](int kt, bf16* buf) {
    gload16(aptr(r0, kt, kc0), buf + d0);
    gload16(aptr(r1, kt, kc1), buf + d1);
  };

  // W fragment source: [panel][kt][wg][gf][lane][8]
  const bf16* wfbase = Wf + (size_t)(tn >> 8) * NT * 8192 + wg * 4096 + lane * 8;
  auto loadW = [&](bf16x8 (&wf)[8], int kt) {
    const bf16* p = wfbase + (size_t)kt * 8192;
    #pragma unroll
    for (int gf = 0; gf < 8; ++gf)
      wf[gf] = *reinterpret_cast<const bf16x8*>(p + gf * 512);
  };

  bf16x8 wfA[8], wfB[8];

  // prologue: A(0)[2], wf(0)[8], A(1)[2] -> allow 10 newest outstanding = A(0) done
  stageA(0, As);
  loadW(wfA, 0);
  stageA(1, As + 4096);
  asm volatile("s_waitcnt vmcnt(10)" ::: "memory");
  SB(); BAR(); SB();

  auto iter = [&](int kt, bf16x8 (&cur)[8], bf16x8 (&nxt)[8]) {
    bf16* buf = As + ((kt & 1) ? 4096 : 0);
    bf16x8 af[4];
    #pragma unroll
    for (int bf = 0; bf < 4; ++bf)
      af[bf] = *reinterpret_cast<const bf16x8*>(&buf[(wb * 64 + bf * 16 + lrow) * 32 + klocal]);
    asm volatile("s_waitcnt lgkmcnt(0)" ::: "memory");
    SB(); BAR(); SB();                     // all waves done reading buf
    if (kt + 2 < NT) stageA(kt + 2, buf);  // overwrite just-read buffer
    if (kt + 1 < NT) loadW(nxt, kt + 1);   // plain global loads, 1 iter ahead
    SB();
    __builtin_amdgcn_s_setprio(1);
    #pragma unroll
    for (int gf = 0; gf < 8; ++gf)
      #pragma unroll
      for (int bf = 0; bf < 4; ++bf)
        acc[gf][bf] = __builtin_amdgcn_mfma_f32_16x16x32_bf16(cur[gf], af[bf], acc[gf][bf], 0, 0, 0);
    __builtin_amdgcn_s_setprio(0);
    // wait A(kt+1) landed: outstanding newer = stageA(kt+2)[2] + loadW(kt+1)[8]
    if (kt + 2 < NT)      { asm volatile("s_waitcnt vmcnt(10)" ::: "memory"); }
    else if (kt + 1 < NT) { asm volatile("s_waitcnt vmcnt(8)" ::: "memory"); }
    else                  { asm volatile("s_waitcnt vmcnt(0)" ::: "memory"); }
    SB(); BAR(); SB();
  };

  for (int kt = 0; kt < NT; kt += 2) {
    iter(kt,     wfA, wfB);
    iter(kt + 1, wfB, wfA);
  }

  // ---- fused cell epilogue (hst = per-wave private 4KB region of As) ----
  bf16* hst = As + w * 2048;            // [64 b][32 h] bf16
  const int hq = (tn >> 2) + wg * 32;   // wave h base (32 h values)
  const int bgb = tm + wb * 64;         // wave batch base (64 rows)
  float yp[4] = {0.f, 0.f, 0.f, 0.f};

  #pragma unroll
  for (int gf = 0; gf < 8; ++gf) {
    int hg = hq + gf * 4 + u;
    f32x4 bv = *reinterpret_cast<const f32x4*>(&bperm[hg * 4]);
    float wph = 0.f;
    if constexpr (MODE == 1) wph = wp[hg];
    #pragma unroll
    for (int bf = 0; bf < 4; ++bf) {
      int bg = bgb + bf * 16 + lrow;
      float gi = acc[gf][bf][0] + bv[0];
      float gf_ = acc[gf][bf][1] + bv[1];
      float gg = acc[gf][bf][2] + bv[2];
      float go = acc[gf][bf][3] + bv[3];
      float* cp_ = ct + (size_t)hg * BB + bg;
      float c = *cp_;
      float cn = sigm(gf_) * c + sigm(gi) * ftanh(gg);
      float hn = sigm(go) * ftanh(cn);
      *cp_ = cn;
      hst[(bf * 16 + lrow) * 32 + gf * 4 + u] = (bf16)hn;
      if constexpr (MODE == 1) yp[bf] += hn * wph;
    }
  }

  asm volatile("s_waitcnt lgkmcnt(0)" ::: "memory");
  SB();

  // coalesced Hout write-out: wave patch = 64 batch x 32 h
  #pragma unroll
  for (int q = 0; q < 4; ++q) {
    int chunk = q * 64 + lane;          // 0..255
    int row = chunk >> 2, seg = chunk & 3;
    bf16x8 v = *reinterpret_cast<const bf16x8*>(&hst[row * 32 + seg * 8]);
    *reinterpret_cast<bf16x8*>(&Hout[(size_t)(bgb + row) * 1024 + hq + seg * 8]) = v;
  }

  if constexpr (MODE == 1) {
    #pragma unroll
    for (int bf = 0; bf < 4; ++bf) {
      float s = yp[bf];
      s += __shfl_xor(s, 16);
      s += __shfl_xor(s, 32);
      if (lane < 16)
        atomicAdd(&y[(size_t)(bgb + bf * 16 + lane) * TT + t], s);
    }
  } else {
    // init y[:, t] = b_proj before dispatch t's L2 atomics (tn==0 blocks)
    if (tn == 0 && tid < 128) y[(size_t)(tm + tid) * TT + t] = bp[0];
  }
}

// Grid 512: bids [0,256) = L2(t); [256,512) = L1(t+1) -> each CU gets one of
// each (scheduler fills round-robin), 64+34 = 98 iters balanced.
// Decode (XCD-stable panels): x=v&7, r=v>>3: tm=(r&15)*128, tn=(x*2+(r>>4))*256.
__global__ __launch_bounds__(256, 2) void step_kernel(
    const bf16* __restrict__ H1in, const bf16* __restrict__ H2in,
    bf16* __restrict__ H1out, bf16* __restrict__ H2out,
    const bf16* __restrict__ X,
    const bf16* __restrict__ Wf0, const bf16* __restrict__ Wf1,
    const float* __restrict__ b0p, const float* __restrict__ b1p,
    float* __restrict__ c1t, float* __restrict__ c2t,
    const float* __restrict__ wp, const float* __restrict__ bp,
    float* __restrict__ y, int t2, int only_l1) {
  __shared__ alignas(16) bf16 As[2 * 4096];   // 16 KB
  int bid = (int)blockIdx.x;
  if (only_l1 || bid >= 256) {
    int v = only_l1 ? bid : bid - 256;        // [0,256)
    int t1 = t2 + 1;
    if (t1 >= TT) return;
    int x = v & 7, r = v >> 3;
    int tm = (r & 15) << 7;
    int tn = ((x << 1) + (r >> 4)) << 8;
    body<0>(tm, tn, t1, X, H1in, Wf0, b0p, c1t, H1out, nullptr, bp, y, As);
  } else {
    int x = bid & 7, r = bid >> 3;
    int tm = (r & 15) << 7;
    int tn = ((x << 1) + (r >> 4)) << 8;
    body<1>(tm, tn, t2, H1in, H2in, Wf1, b1p, c2t, H2out, wp, nullptr, y, As);
  }
}

// ---------------- launch ----------------

extern "C" void kernel_launch(void* const* d_in, const int* in_sizes, int n_in,
                              void* d_out, int out_size, void* d_ws, size_t ws_size,
                              hipStream_t stream) {
  const float* dec   = (const float*)d_in[0];
  const float* ty    = (const float*)d_in[1];
  const float* enc_h = (const float*)d_in[2];
  const float* enc_c = (const float*)d_in[3];
  const float* lec   = (const float*)d_in[4];
  const int*   gid   = (const int*)d_in[5];
  const int*   cp    = (const int*)d_in[6];
  const int*   cct   = (const int*)d_in[7];
  const int*   cpt   = (const int*)d_in[8];
  const int*   ccl   = (const int*)d_in[9];
  const float* gemb  = (const float*)d_in[10];
  const float* ep    = (const float*)d_in[11];
  const float* ect   = (const float*)d_in[12];
  const float* ept   = (const float*)d_in[13];
  const float* ecl   = (const float*)d_in[14];
  const float* Wih0  = (const float*)d_in[15];
  const float* Whh0  = (const float*)d_in[16];
  const float* b0    = (const float*)d_in[17];
  const float* Wih1  = (const float*)d_in[18];
  const float* Whh1  = (const float*)d_in[19];
  const float* b1    = (const float*)d_in[20];
  const float* wp    = (const float*)d_in[21];
  const float* bp    = (const float*)d_in[22];
  float* y = (float*)d_out;

  char* ws = (char*)d_ws;
  bf16* Wf1   = (bf16*)ws;  ws += (size_t)16 * NT1 * 8192 * 2;  // 16.8 MB
  bf16* Wf0   = (bf16*)ws;  ws += (size_t)16 * NT0 * 8192 * 2;  //  8.9 MB
  bf16* X     = (bf16*)ws;  ws += (size_t)BB * TT * 64 * 2;     // 25.2 MB
  bf16* H1a   = (bf16*)ws;  ws += (size_t)BB * 1024 * 2;        //  4.2 MB each
  bf16* H1b   = (bf16*)ws;  ws += (size_t)BB * 1024 * 2;
  bf16* H2a   = (bf16*)ws;  ws += (size_t)BB * 1024 * 2;
  bf16* H2b   = (bf16*)ws;  ws += (size_t)BB * 1024 * 2;
  float* c1t  = (float*)ws; ws += (size_t)BB * 1024 * 4;        //  8.4 MB
  float* c2t  = (float*)ws; ws += (size_t)BB * 1024 * 4;        //  8.4 MB
  float* b0p  = (float*)ws; ws += (size_t)NG * 4;
  float* b1p  = (float*)ws; ws += (size_t)NG * 4;

  build_wf1<<<(16 * NT1 * 8192) / 256, 256, 0, stream>>>(Wih1, Whh1, Wf1);
  build_wf0<<<(16 * NT0 * 8192 + 255) / 256, 256, 0, stream>>>(Wih0, Whh0, Wf0);
  perm_bias<<<NG / 256, 256, 0, stream>>>(b0, b1, b0p, b1p);
  build_x<<<(BB * TT + 255) / 256, 256, 0, stream>>>(dec, ty, lec, gid, cp, cct, cpt, ccl,
                                                     gemb, ep, ect, ept, ecl, X);
  init_state<<<(BB * 1024) / 256, 256, 0, stream>>>(enc_h, enc_c, H1b, H2b, c1t, c2t);

  // prologue: L1(0) alone (grid 256). h1(t) in H1[t&1]; h2(t) in H2[t&1].
  step_kernel<<<256, 256, 0, stream>>>(H1b, nullptr, H1a, nullptr, X, Wf0, Wf1,
                                       b0p, b1p, c1t, c2t, wp, bp, y, -1, 1);
  for (int t = 0; t < TT; ++t) {
    bf16* h1i = (t & 1) ? H1b : H1a;
    bf16* h1o = (t & 1) ? H1a : H1b;
    bf16* h2i = (t & 1) ? H2a : H2b;
    bf16* h2o = (t & 1) ? H2b : H2a;
    step_kernel<<<512, 256, 0, stream>>>(h1i, h2i, h1o, h2o, X, Wf0, Wf1,
                                         b0p, b1p, c1t, c2t, wp, bp, y, t, 0);
  }
}

// Round 14
// 5921.480 us; speedup vs baseline: 1.3734x; 1.0795x over previous
//
#include <hip/hip_runtime.h>
#include <hip/hip_bf16.h>
#include <stdint.h>

// Decoder: 2-layer LSTM, B=2048, T=96, H=1024, teacher forcing=1.0.
// Round 14: BOTH operands as register fragments from pre-arranged global
// buffers. A (H/X) stored 16x8-tiled so a wave's af load = one coalesced 1KB
// dwordx4; W in R13's fragment layout. K-loop: zero LDS, zero barriers, zero
// explicit waitcnts — pure {prefetch(kt+1) -> 32 MFMA}, compiler-pipelined.
// LDS only for the epilogue h-transpose. Grid 512 = 256 L2 + 256 L1 paired.

#define BB  2048
#define TT  96
#define NG  4096
#define NT0 34        // L1 K-iters (K=1088 = 2x32 x-part + 32x32 h-part)
#define NT1 64        // L2 K-iters (K=2048)

typedef __bf16 bf16;
typedef __bf16 bf16x8 __attribute__((ext_vector_type(8)));
typedef float  f32x4  __attribute__((ext_vector_type(4)));

__device__ __forceinline__ float sigm(float x) { return 1.0f / (1.0f + __expf(-x)); }
__device__ __forceinline__ float ftanh(float x) { return 2.0f / (1.0f + __expf(-2.0f * x)) - 1.0f; }

#define SB() __builtin_amdgcn_sched_barrier(0)

// ---------------- prep kernels ----------------
// Gate-interleaved n' = h*4 + gate (orig row n = (n'&3)*1024 + (n'>>2)).
// Wfrag: [panel(256g)][kt][wg(2)][gf(8)][lane(64)][j(8)] (R13 layout).
// Afrag (H, X): tile (b>>4, k>>3) of 16x8 stored contiguous 128 elems:
//   off = ((b>>4)*K8 + (k>>3))*128 + (b&15)*8 + (k&7);  K8 = 128 (H), 8 (X).

__global__ __launch_bounds__(256) void build_wf1(const float* __restrict__ Wih1,
                                                 const float* __restrict__ Whh1,
                                                 bf16* __restrict__ Wf) {
  int idx = blockIdx.x * 256 + threadIdx.x;      // 16*64*8192
  if (idx >= 16 * NT1 * 8192) return;
  int j = idx & 7, lane = (idx >> 3) & 63, gf = (idx >> 9) & 7;
  int wg = (idx >> 12) & 1, kt = (idx >> 13) & 63, panel = idx >> 19;
  int np = panel * 256 + wg * 128 + gf * 16 + (lane & 15);
  int k  = kt * 32 + ((lane >> 4) << 3) + j;
  int n  = (np & 3) * 1024 + (np >> 2);
  float v = (k < 1024) ? Wih1[n * 1024 + k] : Whh1[n * 1024 + (k - 1024)];
  Wf[idx] = (bf16)v;
}

__global__ __launch_bounds__(256) void build_wf0(const float* __restrict__ Wih0,
                                                 const float* __restrict__ Whh0,
                                                 bf16* __restrict__ Wf) {
  int idx = blockIdx.x * 256 + threadIdx.x;      // 16*34*8192
  if (idx >= 16 * NT0 * 8192) return;
  int j = idx & 7, lane = (idx >> 3) & 63, gf = (idx >> 9) & 7;
  int wg = (idx >> 12) & 1;
  int rem = idx >> 13;
  int kt = rem % NT0, panel = rem / NT0;
  int np = panel * 256 + wg * 128 + gf * 16 + (lane & 15);
  int k  = kt * 32 + ((lane >> 4) << 3) + j;
  int n  = (np & 3) * 1024 + (np >> 2);
  float v;
  if (k < 60)      v = Wih0[n * 60 + k];
  else if (k < 64) v = 0.0f;
  else             v = Whh0[n * 1024 + (k - 64)];
  Wf[idx] = (bf16)v;
}

__global__ __launch_bounds__(256) void perm_bias(const float* __restrict__ b0,
                                                 const float* __restrict__ b1,
                                                 float* __restrict__ b0p,
                                                 float* __restrict__ b1p) {
  int idx = blockIdx.x * 256 + threadIdx.x;
  if (idx >= NG) return;
  int n = (idx & 3) * 1024 + (idx >> 2);
  b0p[idx] = b0[n];
  b1p[idx] = b1[n];
}

// Xf: per-t slab of 2048*64 elems, 16x8-tiled (K8 = 8)
__global__ __launch_bounds__(256) void build_xf(
    const float* __restrict__ dec, const float* __restrict__ ty, const float* __restrict__ lec,
    const int* __restrict__ gid, const int* __restrict__ cp, const int* __restrict__ cct,
    const int* __restrict__ cpt, const int* __restrict__ ccl,
    const float* __restrict__ gemb, const float* __restrict__ ep, const float* __restrict__ ect,
    const float* __restrict__ ept, const float* __restrict__ ecl,
    bf16* __restrict__ Xf) {
  int idx = blockIdx.x * 256 + threadIdx.x;  // over B*T
  if (idx >= BB * TT) return;
  int b = idx / TT, t = idx % TT;
  float xv[64];
  xv[0] = (t == 0) ? lec[b] : ty[b * TT + t - 1];
  const float* d = dec + (size_t)idx * 32;
  #pragma unroll
  for (int k = 0; k < 32; ++k) xv[1 + k] = d[k];
  const float* e;
  e = ep  + cp[b]  * 4;  for (int j = 0; j < 4;  ++j) xv[33 + j] = e[j];
  e = ect + cct[b] * 2;  for (int j = 0; j < 2;  ++j) xv[37 + j] = e[j];
  e = ept + cpt[b] * 3;  for (int j = 0; j < 3;  ++j) xv[39 + j] = e[j];
  e = ecl + ccl[b] * 2;  for (int j = 0; j < 2;  ++j) xv[42 + j] = e[j];
  e = gemb + gid[b] * 16; for (int j = 0; j < 16; ++j) xv[44 + j] = e[j];
  for (int j = 60; j < 64; ++j) xv[j] = 0.0f;
  bf16* slab = Xf + (size_t)t * BB * 64;
  int bt = b >> 4, bl = b & 15;
  #pragma unroll
  for (int k = 0; k < 64; ++k)
    slab[((size_t)(bt * 8 + (k >> 3)) << 7) + bl * 8 + (k & 7)] = (bf16)xv[k];
}

// enc state -> Hf fragment layout (K8=128) + transposed c ([h][b])
__global__ __launch_bounds__(256) void init_state(const float* __restrict__ enc_h,
                                                  const float* __restrict__ enc_c,
                                                  bf16* __restrict__ H1b,
                                                  bf16* __restrict__ H2b,
                                                  float* __restrict__ c1t,
                                                  float* __restrict__ c2t) {
  int idx = blockIdx.x * 256 + threadIdx.x;  // over B*H
  if (idx >= BB * 1024) return;
  int b = idx >> 10, h = idx & 1023;
  size_t off = ((size_t)((b >> 4) * 128 + (h >> 3)) << 7) + ((b & 15) << 3) + (h & 7);
  H1b[off] = (bf16)enc_h[idx];
  H2b[off] = (bf16)enc_h[(size_t)BB * 1024 + idx];
  c1t[(size_t)h * BB + b] = enc_c[idx];
  c2t[(size_t)h * BB + b] = enc_c[(size_t)BB * 1024 + idx];
}

// ---------------- streaming GEMM + fused cell: 128b x 256g, 4 waves --------
// gates(b,n') = A(b,:).W(n',:). mfma(wf, af): lane's f32x4 = {i,f,g,o} of one
// (b,h) cell: h = (tn>>2) + wg*32 + gf*4 + u, b = tm + wb*64 + bf*16 + l15.
// Both operands stream global->reg (L1/L2-resident), no LDS/barriers in loop.

template <int MODE>
__device__ __forceinline__ void body(
    int tm, int tn, int t,
    const bf16* __restrict__ P0, const bf16* __restrict__ P1,
    const bf16* __restrict__ Wf, const float* __restrict__ bperm,
    float* __restrict__ ct, bf16* __restrict__ Hout,
    const float* __restrict__ wp, const float* __restrict__ bp,
    float* __restrict__ y, bf16* hst_all)
{
  constexpr int NT = MODE ? NT1 : NT0;

  const int tid = threadIdx.x;
  const int lane = tid & 63, w = tid >> 6;
  const int lrow = lane & 15, u = lane >> 4;
  const int wb = w & 1, wg = w >> 1;

  f32x4 acc[8][4];
  #pragma unroll
  for (int gf = 0; gf < 8; ++gf)
    #pragma unroll
    for (int bf = 0; bf < 4; ++bf) acc[gf][bf] = (f32x4){0.f, 0.f, 0.f, 0.f};

  // A fragments: per-wave 1KB coalesced chunk per bf
  const int aoff = (u << 7) + (lrow << 3);       // lane offset within 512-elem chunk
  const int BtB = (tm >> 4) + wb * 4;            // base b-tile

  auto loadA = [&](bf16x8 (&af)[4], int kt) {
    #pragma unroll
    for (int bf = 0; bf < 4; ++bf) {
      const bf16* p;
      if constexpr (MODE == 0) {
        p = (kt < 2) ? P0 + ((size_t)((BtB + bf) * 8 + kt * 4) << 7) + aoff
                     : P1 + ((size_t)((BtB + bf) * 128 + (kt - 2) * 4) << 7) + aoff;
      } else {
        p = (kt < 32) ? P0 + ((size_t)((BtB + bf) * 128 + kt * 4) << 7) + aoff
                      : P1 + ((size_t)((BtB + bf) * 128 + (kt - 32) * 4) << 7) + aoff;
      }
      af[bf] = *reinterpret_cast<const bf16x8*>(p);
    }
  };

  // W fragments: [panel][kt][wg][gf][lane][8]
  const bf16* wfbase = Wf + (size_t)(tn >> 8) * NT * 8192 + wg * 4096 + lane * 8;
  auto loadW = [&](bf16x8 (&wf)[8], int kt) {
    const bf16* p = wfbase + (size_t)kt * 8192;
    #pragma unroll
    for (int gf = 0; gf < 8; ++gf)
      wf[gf] = *reinterpret_cast<const bf16x8*>(p + gf * 512);
  };

  bf16x8 afA[4], afB[4], wfA[8], wfB[8];

  loadA(afA, 0); loadW(wfA, 0);
  for (int kt = 0; kt < NT; kt += 2) {
    if (kt + 1 < NT) { loadA(afB, kt + 1); loadW(wfB, kt + 1); }
    SB();
    __builtin_amdgcn_s_setprio(1);
    #pragma unroll
    for (int gf = 0; gf < 8; ++gf)
      #pragma unroll
      for (int bf = 0; bf < 4; ++bf)
        acc[gf][bf] = __builtin_amdgcn_mfma_f32_16x16x32_bf16(wfA[gf], afA[bf], acc[gf][bf], 0, 0, 0);
    __builtin_amdgcn_s_setprio(0);
    if (kt + 2 < NT) { loadA(afA, kt + 2); loadW(wfA, kt + 2); }
    SB();
    __builtin_amdgcn_s_setprio(1);
    #pragma unroll
    for (int gf = 0; gf < 8; ++gf)
      #pragma unroll
      for (int bf = 0; bf < 4; ++bf)
        acc[gf][bf] = __builtin_amdgcn_mfma_f32_16x16x32_bf16(wfB[gf], afB[bf], acc[gf][bf], 0, 0, 0);
    __builtin_amdgcn_s_setprio(0);
  }

  // ---- fused cell epilogue (per-wave private LDS transpose; no barriers) ----
  bf16* hst = hst_all + w * 2048;       // [64 b][32 h] bf16
  const int hq = (tn >> 2) + wg * 32;   // wave h base (32 h values)
  const int bgb = tm + wb * 64;         // wave batch base (64 rows)
  float yp[4] = {0.f, 0.f, 0.f, 0.f};

  #pragma unroll
  for (int gf = 0; gf < 8; ++gf) {
    int hg = hq + gf * 4 + u;
    f32x4 bv = *reinterpret_cast<const f32x4*>(&bperm[hg * 4]);
    float wph = 0.f;
    if constexpr (MODE == 1) wph = wp[hg];
    #pragma unroll
    for (int bf = 0; bf < 4; ++bf) {
      int bg = bgb + bf * 16 + lrow;
      float gi = acc[gf][bf][0] + bv[0];
      float gf_ = acc[gf][bf][1] + bv[1];
      float gg = acc[gf][bf][2] + bv[2];
      float go = acc[gf][bf][3] + bv[3];
      float* cp_ = ct + (size_t)hg * BB + bg;
      float c = *cp_;
      float cn = sigm(gf_) * c + sigm(gi) * ftanh(gg);
      float hn = sigm(go) * ftanh(cn);
      *cp_ = cn;
      hst[(bf * 16 + lrow) * 32 + gf * 4 + u] = (bf16)hn;
      if constexpr (MODE == 1) yp[bf] += hn * wph;
    }
  }

  asm volatile("s_waitcnt lgkmcnt(0)" ::: "memory");
  SB();

  // H write in fragment layout: chunk row=b_local (0..63), seg = 8-h group.
  #pragma unroll
  for (int q = 0; q < 4; ++q) {
    int chunk = q * 64 + lane;          // 0..255
    int row = chunk >> 2, seg = chunk & 3;
    bf16x8 v = *reinterpret_cast<const bf16x8*>(&hst[row * 32 + seg * 8]);
    size_t off = ((size_t)(((bgb >> 4) + (row >> 4)) * 128 + (hq >> 3) + seg) << 7)
               + ((row & 15) << 3);
    *reinterpret_cast<bf16x8*>(&Hout[off]) = v;
  }

  if constexpr (MODE == 1) {
    #pragma unroll
    for (int bf = 0; bf < 4; ++bf) {
      float s = yp[bf];
      s += __shfl_xor(s, 16);
      s += __shfl_xor(s, 32);
      if (lane < 16)
        atomicAdd(&y[(size_t)(bgb + bf * 16 + lane) * TT + t], s);
    }
  } else {
    if (tn == 0 && tid < 128) y[(size_t)(tm + tid) * TT + t] = bp[0];
  }
}

// Grid 512: bids [0,256) = L2(t); [256,512) = L1(t+1) (CU pairs one of each).
// Decode (XCD-stable panels): x=v&7, r=v>>3: tm=(r&15)*128, tn=(x*2+(r>>4))*256.
__global__ __launch_bounds__(256, 2) void step_kernel(
    const bf16* __restrict__ H1in, const bf16* __restrict__ H2in,
    bf16* __restrict__ H1out, bf16* __restrict__ H2out,
    const bf16* __restrict__ Xf,
    const bf16* __restrict__ Wf0, const bf16* __restrict__ Wf1,
    const float* __restrict__ b0p, const float* __restrict__ b1p,
    float* __restrict__ c1t, float* __restrict__ c2t,
    const float* __restrict__ wp, const float* __restrict__ bp,
    float* __restrict__ y, int t2, int only_l1) {
  __shared__ alignas(16) bf16 hst_all[4 * 2048];   // 16 KB (epilogue only)
  int bid = (int)blockIdx.x;
  if (only_l1 || bid >= 256) {
    int v = only_l1 ? bid : bid - 256;
    int t1 = t2 + 1;
    if (t1 >= TT) return;
    int x = v & 7, r = v >> 3;
    int tm = (r & 15) << 7;
    int tn = ((x << 1) + (r >> 4)) << 8;
    body<0>(tm, tn, t1, Xf + (size_t)t1 * BB * 64, H1in,
            Wf0, b0p, c1t, H1out, nullptr, bp, y, hst_all);
  } else {
    int x = bid & 7, r = bid >> 3;
    int tm = (r & 15) << 7;
    int tn = ((x << 1) + (r >> 4)) << 8;
    body<1>(tm, tn, t2, H1in, H2in,
            Wf1, b1p, c2t, H2out, wp, nullptr, y, hst_all);
  }
}

// ---------------- launch ----------------

extern "C" void kernel_launch(void* const* d_in, const int* in_sizes, int n_in,
                              void* d_out, int out_size, void* d_ws, size_t ws_size,
                              hipStream_t stream) {
  const float* dec   = (const float*)d_in[0];
  const float* ty    = (const float*)d_in[1];
  const float* enc_h = (const float*)d_in[2];
  const float* enc_c = (const float*)d_in[3];
  const float* lec   = (const float*)d_in[4];
  const int*   gid   = (const int*)d_in[5];
  const int*   cp    = (const int*)d_in[6];
  const int*   cct   = (const int*)d_in[7];
  const int*   cpt   = (const int*)d_in[8];
  const int*   ccl   = (const int*)d_in[9];
  const float* gemb  = (const float*)d_in[10];
  const float* ep    = (const float*)d_in[11];
  const float* ect   = (const float*)d_in[12];
  const float* ept   = (const float*)d_in[13];
  const float* ecl   = (const float*)d_in[14];
  const float* Wih0  = (const float*)d_in[15];
  const float* Whh0  = (const float*)d_in[16];
  const float* b0    = (const float*)d_in[17];
  const float* Wih1  = (const float*)d_in[18];
  const float* Whh1  = (const float*)d_in[19];
  const float* b1    = (const float*)d_in[20];
  const float* wp    = (const float*)d_in[21];
  const float* bp    = (const float*)d_in[22];
  float* y = (float*)d_out;

  char* ws = (char*)d_ws;
  bf16* Wf1   = (bf16*)ws;  ws += (size_t)16 * NT1 * 8192 * 2;  // 16.8 MB
  bf16* Wf0   = (bf16*)ws;  ws += (size_t)16 * NT0 * 8192 * 2;  //  8.9 MB
  bf16* Xf    = (bf16*)ws;  ws += (size_t)BB * TT * 64 * 2;     // 25.2 MB
  bf16* H1a   = (bf16*)ws;  ws += (size_t)BB * 1024 * 2;        //  4.2 MB each
  bf16* H1b   = (bf16*)ws;  ws += (size_t)BB * 1024 * 2;
  bf16* H2a   = (bf16*)ws;  ws += (size_t)BB * 1024 * 2;
  bf16* H2b   = (bf16*)ws;  ws += (size_t)BB * 1024 * 2;
  float* c1t  = (float*)ws; ws += (size_t)BB * 1024 * 4;        //  8.4 MB
  float* c2t  = (float*)ws; ws += (size_t)BB * 1024 * 4;        //  8.4 MB
  float* b0p  = (float*)ws; ws += (size_t)NG * 4;
  float* b1p  = (float*)ws; ws += (size_t)NG * 4;

  build_wf1<<<(16 * NT1 * 8192) / 256, 256, 0, stream>>>(Wih1, Whh1, Wf1);
  build_wf0<<<(16 * NT0 * 8192 + 255) / 256, 256, 0, stream>>>(Wih0, Whh0, Wf0);
  perm_bias<<<NG / 256, 256, 0, stream>>>(b0, b1, b0p, b1p);
  build_xf<<<(BB * TT + 255) / 256, 256, 0, stream>>>(dec, ty, lec, gid, cp, cct, cpt, ccl,
                                                      gemb, ep, ect, ept, ecl, Xf);
  init_state<<<(BB * 1024) / 256, 256, 0, stream>>>(enc_h, enc_c, H1b, H2b, c1t, c2t);

  // prologue: L1(0) alone (grid 256). h1(t) in H1[t&1]; h2(t) in H2[t&1].
  step_kernel<<<256, 256, 0, stream>>>(H1b, nullptr, H1a, nullptr, Xf, Wf0, Wf1,
                                       b0p, b1p, c1t, c2t, wp, bp, y, -1, 1);
  for (int t = 0; t < TT; ++t) {
    bf16* h1i = (t & 1) ? H1b : H1a;
    bf16* h1o = (t & 1) ? H1a : H1b;
    bf16* h2i = (t & 1) ? H2a : H2b;
    bf16* h2o = (t & 1) ? H2b : H2a;
    step_kernel<<<512, 256, 0, stream>>>(h1i, h2i, h1o, h2o, Xf, Wf0, Wf1,
                                         b0p, b1p, c1t, c2t, wp, bp, y, t, 0);
  }
}